// Round 1
// baseline (437.547 us; speedup 1.0000x reference)
//
#include <hip/hip_runtime.h>
#include <stdint.h>

#define W 768
#define NPROB (768*768)
#define NB 8
#define NBINS 2048
#define CAP 4096
#define TOPK 2048
#define SCORE_THR 0.6f

// ws layout (bytes)
#define HIST_OFF  0
#define HIST_BYTES (NB*NBINS*4)            // 65536
#define META_OFF  (HIST_OFF + HIST_BYTES)  // 65536
#define CAND_OFF  (META_OFF + 256)         // 65792
#define CAND_BYTES (NB*CAP*8)              // 262144
#define ZERO_BYTES (CAND_OFF + CAND_BYTES) // 327936
#define SKEY_OFF  ZERO_BYTES               // 327936
#define SKEY_BYTES (NB*TOPK*8)             // 131072
#define NBR_OFF   (SKEY_OFF + SKEY_BYTES)  // 459008
#define NBR_BYTES (NB*TOPK*2*8)            // 262144
#define NCNT_OFF  (NBR_OFF + NBR_BYTES)    // 721152
#define NCNT_BYTES (NB*TOPK)               // 16384
#define WS_TOTAL  (NCNT_OFF + NCNT_BYTES)  // 737536

struct Meta { unsigned bstar; unsigned c1; unsigned cnt; unsigned pad; };

// bin over float bits: valid scores are in [0.6,1.0) -> one binade, bits monotone
__device__ __forceinline__ unsigned score_bin(unsigned fb) {
    return (fb >> 13) & 0x7FFu;
}

__global__ __launch_bounds__(256) void hist_kernel(const float* __restrict__ probs,
                                                   unsigned* __restrict__ hist) {
    __shared__ unsigned lh[NBINS];
    int b = blockIdx.y;
    for (int i = threadIdx.x; i < NBINS; i += 256) lh[i] = 0;
    __syncthreads();
    const int per = NPROB / 36;   // gridDim.x == 36, 589824 = 36*16384
    int base = blockIdx.x * per;
    const float* p = probs + (size_t)b * NPROB + base;
    for (int i = threadIdx.x; i < per; i += 256) {
        float s = p[i];
        if (s >= SCORE_THR) atomicAdd(&lh[score_bin(__float_as_uint(s))], 1u);
    }
    __syncthreads();
    unsigned* gh = hist + b * NBINS;
    for (int i = threadIdx.x; i < NBINS; i += 256) {
        unsigned v = lh[i];
        if (v) atomicAdd(&gh[i], v);
    }
}

__global__ __launch_bounds__(256) void select_kernel(const unsigned* __restrict__ hist,
                                                     Meta* __restrict__ meta) {
    int b = blockIdx.x;
    const unsigned* h = hist + b * NBINS;
    __shared__ unsigned partial[256];
    int t = threadIdx.x;
    unsigned s = 0;
    for (int i = 0; i < NBINS/256; ++i) s += h[t * (NBINS/256) + i];
    partial[t] = s;
    __syncthreads();
    if (t == 0) {
        const int CH = NBINS / 256;  // 8 bins per chunk
        unsigned cum = 0;
        int chunk = 255;
        for (; chunk >= 0; --chunk) {
            if (cum + partial[chunk] >= TOPK) break;
            cum += partial[chunk];
        }
        unsigned bstar = 0, c1 = cum;
        if (chunk >= 0) {
            int bin = chunk * CH + CH - 1;
            for (; bin >= chunk * CH; --bin) {
                unsigned v = h[bin];
                if (cum + v >= TOPK) break;
                cum += v;
            }
            bstar = (unsigned)bin;
            c1 = cum;
        }
        meta[b].bstar = bstar;
        meta[b].c1 = c1;
    }
}

__global__ __launch_bounds__(256) void compact_kernel(const float* __restrict__ probs,
                                                      Meta* __restrict__ meta,
                                                      unsigned long long* __restrict__ cand) {
    int b = blockIdx.y;
    int i = blockIdx.x * 256 + threadIdx.x;
    float s = probs[(size_t)b * NPROB + i];
    if (s >= SCORE_THR) {
        unsigned fb = __float_as_uint(s);
        if (score_bin(fb) >= meta[b].bstar) {
            unsigned pos = atomicAdd(&meta[b].cnt, 1u);
            if (pos < CAP) {
                unsigned long long key = ((unsigned long long)fb << 32) | (unsigned)(~(unsigned)i);
                cand[(size_t)b * CAP + pos] = key;
            }
        }
    }
}

__global__ __launch_bounds__(1024) void sort_kernel(const unsigned long long* __restrict__ cand,
                                                    unsigned long long* __restrict__ skey) {
    int b = blockIdx.x;
    __shared__ unsigned long long keys[CAP];   // 32 KB
    for (int i = threadIdx.x; i < CAP; i += 1024)
        keys[i] = cand[(size_t)b * CAP + i];
    __syncthreads();
    // bitonic sort, descending (zeros/padding sink to the end)
    for (int k2 = 2; k2 <= CAP; k2 <<= 1) {
        for (int j = k2 >> 1; j > 0; j >>= 1) {
            for (int idx = threadIdx.x; idx < CAP; idx += 1024) {
                int l = idx ^ j;
                if (l > idx) {
                    unsigned long long a = keys[idx], c = keys[l];
                    bool up = ((idx & k2) == 0);
                    if ((a < c) == up) { keys[idx] = c; keys[l] = a; }
                }
            }
            __syncthreads();
        }
    }
    for (int i = threadIdx.x; i < TOPK; i += 1024)
        skey[(size_t)b * TOPK + i] = keys[i];
}

// Build per-box list of EARLIER adjacent boxes (Chebyshev<=1 on grid cells).
// Max 8 earlier neighbors per box (8 distinct neighbor cells, unique indices).
__global__ __launch_bounds__(256) void nbr_kernel(const unsigned long long* __restrict__ skey,
                                                  unsigned long long* __restrict__ nbr2,
                                                  unsigned char* __restrict__ ncnt) {
    int b = blockIdx.y;
    __shared__ unsigned pc[TOPK];
    for (int i = threadIdx.x; i < TOPK; i += 256) {
        unsigned long long key = skey[(size_t)b * TOPK + i];
        unsigned pcv;
        if (key != 0ULL) {
            unsigned idx = ~(unsigned)key;
            pcv = ((idx / W) << 16) | (idx % W);
        } else {
            // far-away sentinel, spaced so pads are not adjacent to anything
            pcv = 0x40000000u | ((unsigned)i << 2);
        }
        pc[i] = pcv;
    }
    __syncthreads();
    int j = blockIdx.x * 256 + threadIdx.x;  // 0..2047
    unsigned pj = pc[j];
    int yj = (int)(pj >> 16), xj = (int)(pj & 0xFFFFu);
    unsigned long long lp0 = 0, lp1 = 0;
    int cnt = 0;
    for (int i = 0; i < j; ++i) {
        unsigned pi = pc[i];   // broadcast read (same addr across wave)
        int dy = (int)(pi >> 16) - yj;
        int dx = (int)(pi & 0xFFFFu) - xj;
        if ((unsigned)(dy + 1) <= 2u && (unsigned)(dx + 1) <= 2u) {
            if (cnt < 4)      lp0 |= (unsigned long long)(unsigned)i << (cnt * 16);
            else if (cnt < 8) lp1 |= (unsigned long long)(unsigned)i << ((cnt - 4) * 16);
            cnt++;
        }
    }
    if (cnt > 8) cnt = 8;
    ncnt[(size_t)b * TOPK + j] = (unsigned char)cnt;
    size_t ro = ((size_t)b * TOPK + j) * 2;
    nbr2[ro] = lp0;
    nbr2[ro + 1] = lp1;
}

__global__ __launch_bounds__(256) void nms_out_kernel(const float* __restrict__ dev4,
                                                      const unsigned long long* __restrict__ skey,
                                                      const unsigned long long* __restrict__ nbr2,
                                                      const unsigned char* __restrict__ ncnt,
                                                      float* __restrict__ out) {
    int b = blockIdx.x;
    __shared__ unsigned long long s_nbr[TOPK * 2];  // 32 KB
    __shared__ unsigned char s_cnt[TOPK];
    __shared__ unsigned char s_valid[TOPK];
    __shared__ unsigned char s_kept[TOPK];
    __shared__ unsigned short s_dep[TOPK];
    __shared__ unsigned s_part[256];
    int tid = threadIdx.x;

    for (int i = tid; i < TOPK * 2; i += 256)
        s_nbr[i] = nbr2[(size_t)b * TOPK * 2 + i];

    // chunked pass: thread t owns slots [t*8, t*8+8)
    int nd = 0;
    for (int q = 0; q < 8; ++q) {
        int j = tid * 8 + q;
        unsigned long long key = skey[(size_t)b * TOPK + j];
        unsigned char c = ncnt[(size_t)b * TOPK + j];
        unsigned char v = (key != 0ULL) ? 1 : 0;
        s_cnt[j] = c;
        s_valid[j] = v;
        s_kept[j] = (c == 0) ? v : 0;   // no earlier neighbor -> final immediately
        if (c) nd++;
    }
    s_part[tid] = (unsigned)nd;
    __syncthreads();
    // inclusive prefix sum over 256 (Hillis-Steele)
    for (int off = 1; off < 256; off <<= 1) {
        unsigned v = (tid >= off) ? s_part[tid - off] : 0u;
        __syncthreads();
        s_part[tid] += v;
        __syncthreads();
    }
    int pos = (int)s_part[tid] - nd;
    for (int q = 0; q < 8; ++q) {
        int j = tid * 8 + q;
        if (s_cnt[j]) s_dep[pos++] = (unsigned short)j;
    }
    __syncthreads();

    // sequential greedy resolve over only the dependent boxes (ascending j)
    if (tid == 0) {
        int n = (int)s_part[255];
        for (int e = 0; e < n; ++e) {
            int j = (int)s_dep[e];
            unsigned char k = s_valid[j];
            int c = (int)s_cnt[j];
            for (int l = 0; l < c && k; ++l) {
                unsigned long long w = s_nbr[j * 2 + (l >> 2)];
                unsigned id = (unsigned)((w >> ((l & 3) * 16)) & 0xFFFFu);
                if (s_kept[id]) k = 0;
            }
            s_kept[j] = k;
        }
    }
    __syncthreads();

    // refine + write
    for (int j = tid; j < TOPK; j += 256) {
        unsigned long long key = skey[(size_t)b * TOPK + j];
        float o0 = 0.f, o1 = 0.f, o2 = 0.f, o3 = 0.f, o4 = 0.f;
        if (key != 0ULL && s_kept[j]) {
            unsigned idx = ~(unsigned)key;
            float sc = __uint_as_float((unsigned)(key >> 32));
            int y = (int)(idx / W), x = (int)(idx % W);
            const float4 d = ((const float4*)dev4)[(size_t)b * NPROB + idx];
            float b0 = (float)(4 * y + 2);
            float b1 = (float)(4 * x + 2);
            float b2 = (float)(4 * y + 24);
            float b3 = (float)(4 * x + 24);
            float r0 = b0 + d.x * 22.0f;
            float r1 = b1 + d.y * 22.0f;
            float r2 = b2 + d.z * 22.0f;
            float r3 = b3 + d.w * 22.0f;
            float rh = r2 - r0, rw = r3 - r1;
            float len = fmaxf(rh, rw);
            float c0 = r0 + rh * 0.5f, c1v = r1 + rw * 0.5f;
            float u0 = c0 - 0.5f * len, u1 = c1v - 0.5f * len;
            float v0 = u0 + len, v1 = u1 + len;
            o0 = fminf(fmaxf(u0, 1.0f), 3095.0f);
            o1 = fminf(fmaxf(u1, 1.0f), 3095.0f);
            o2 = fminf(fmaxf(v0, 1.0f), 3095.0f);
            o3 = fminf(fmaxf(v1, 1.0f), 3095.0f);
            o4 = sc;
        }
        float* op = out + ((size_t)b * TOPK + j) * 5;
        op[0] = o0; op[1] = o1; op[2] = o2; op[3] = o3; op[4] = o4;
    }
}

extern "C" void kernel_launch(void* const* d_in, const int* in_sizes, int n_in,
                              void* d_out, int out_size, void* d_ws, size_t ws_size,
                              hipStream_t stream) {
    (void)in_sizes; (void)n_in; (void)out_size;
    if (ws_size < (size_t)WS_TOTAL) return;  // defensive: avoid OOB

    const float* probs = (const float*)d_in[0];
    const float* devs  = (const float*)d_in[1];
    float* out = (float*)d_out;
    char* ws = (char*)d_ws;

    unsigned* hist = (unsigned*)(ws + HIST_OFF);
    Meta* meta = (Meta*)(ws + META_OFF);
    unsigned long long* cand = (unsigned long long*)(ws + CAND_OFF);
    unsigned long long* skey = (unsigned long long*)(ws + SKEY_OFF);
    unsigned long long* nbr2 = (unsigned long long*)(ws + NBR_OFF);
    unsigned char* ncnt = (unsigned char*)(ws + NCNT_OFF);

    hipMemsetAsync(d_ws, 0, ZERO_BYTES, stream);

    hist_kernel<<<dim3(36, NB), 256, 0, stream>>>(probs, hist);
    select_kernel<<<NB, 256, 0, stream>>>(hist, meta);
    compact_kernel<<<dim3(NPROB / 256, NB), 256, 0, stream>>>(probs, meta, cand);
    sort_kernel<<<NB, 1024, 0, stream>>>(cand, skey);
    nbr_kernel<<<dim3(TOPK / 256, NB), 256, 0, stream>>>(skey, nbr2, ncnt);
    nms_out_kernel<<<NB, 256, 0, stream>>>(devs, skey, nbr2, ncnt, out);
}

// Round 2
// 249.904 us; speedup vs baseline: 1.7509x; 1.7509x over previous
//
#include <hip/hip_runtime.h>
#include <stdint.h>

#define W 768
#define NPROB (768*768)
#define NB 8
#define NBINS 2048
#define CAP 4096
#define TOPK 2048
#define SCORE_THR 0.6f
#define NBLK 36            // blocks per batch for scan kernels; NPROB = 36*16384

// ws layout (bytes)
#define HIST_OFF  0
#define HIST_BYTES (NB*NBINS*4)            // 65536
#define META_OFF  (HIST_OFF + HIST_BYTES)  // 65536
#define CAND_OFF  (META_OFF + 256)         // 65792
#define CAND_BYTES (NB*CAP*8)              // 262144
#define ZERO_BYTES (CAND_OFF + CAND_BYTES) // 327936
#define SKEY_OFF  ZERO_BYTES               // 327936
#define SKEY_BYTES (NB*TOPK*8)             // 131072
#define NBR_OFF   (SKEY_OFF + SKEY_BYTES)  // 459008
#define NBR_BYTES (NB*TOPK*2*8)            // 262144
#define NCNT_OFF  (NBR_OFF + NBR_BYTES)    // 721152
#define NCNT_BYTES (NB*TOPK)               // 16384
#define WS_TOTAL  (NCNT_OFF + NCNT_BYTES)  // 737536

struct Meta { unsigned bstar; unsigned c1; unsigned cnt; unsigned pad; };

// bin over float bits: valid scores are in [0.6,1.0) -> one binade, bits monotone
__device__ __forceinline__ unsigned score_bin(unsigned fb) {
    return (fb >> 13) & 0x7FFu;
}

__global__ __launch_bounds__(256) void hist_kernel(const float* __restrict__ probs,
                                                   unsigned* __restrict__ hist) {
    __shared__ unsigned lh[NBINS];
    int b = blockIdx.y;
    for (int i = threadIdx.x; i < NBINS; i += 256) lh[i] = 0;
    __syncthreads();
    const int per4 = (NPROB / NBLK) / 4;      // 4096 float4 per block
    const float4* p = (const float4*)(probs + (size_t)b * NPROB) + (size_t)blockIdx.x * per4;
    for (int i = threadIdx.x; i < per4; i += 256) {
        float4 v = p[i];
        if (v.x >= SCORE_THR) atomicAdd(&lh[score_bin(__float_as_uint(v.x))], 1u);
        if (v.y >= SCORE_THR) atomicAdd(&lh[score_bin(__float_as_uint(v.y))], 1u);
        if (v.z >= SCORE_THR) atomicAdd(&lh[score_bin(__float_as_uint(v.z))], 1u);
        if (v.w >= SCORE_THR) atomicAdd(&lh[score_bin(__float_as_uint(v.w))], 1u);
    }
    __syncthreads();
    unsigned* gh = hist + b * NBINS;
    for (int i = threadIdx.x; i < NBINS; i += 256) {
        unsigned v = lh[i];
        if (v) atomicAdd(&gh[i], v);
    }
}

__global__ __launch_bounds__(256) void select_kernel(const unsigned* __restrict__ hist,
                                                     Meta* __restrict__ meta) {
    int b = blockIdx.x;
    const unsigned* h = hist + b * NBINS;
    __shared__ unsigned partial[256];
    int t = threadIdx.x;
    unsigned s = 0;
    for (int i = 0; i < NBINS/256; ++i) s += h[t * (NBINS/256) + i];
    partial[t] = s;
    __syncthreads();
    if (t == 0) {
        const int CH = NBINS / 256;  // 8 bins per chunk
        unsigned cum = 0;
        int chunk = 255;
        for (; chunk >= 0; --chunk) {
            if (cum + partial[chunk] >= TOPK) break;
            cum += partial[chunk];
        }
        unsigned bstar = 0, c1 = cum;
        if (chunk >= 0) {
            int bin = chunk * CH + CH - 1;
            for (; bin >= chunk * CH; --bin) {
                unsigned v = h[bin];
                if (cum + v >= TOPK) break;
                cum += v;
            }
            bstar = (unsigned)bin;
            c1 = cum;
        }
        meta[b].bstar = bstar;
        meta[b].c1 = c1;
    }
}

// Block-local compaction: float4 loads, LDS staging, ONE global atomic per block.
__global__ __launch_bounds__(256) void compact_kernel(const float* __restrict__ probs,
                                                      Meta* __restrict__ meta,
                                                      unsigned long long* __restrict__ cand) {
    __shared__ unsigned long long lbuf[CAP];   // 32 KB
    __shared__ unsigned lcnt;
    __shared__ unsigned gbase;
    int b = blockIdx.y;
    int tid = threadIdx.x;
    if (tid == 0) lcnt = 0;
    __syncthreads();

    unsigned bstar = meta[b].bstar;
    const int per4 = (NPROB / NBLK) / 4;      // 4096 float4 per block
    int base_elem = blockIdx.x * (NPROB / NBLK);
    const float4* p = (const float4*)(probs + (size_t)b * NPROB) + (size_t)blockIdx.x * per4;
    for (int i = tid; i < per4; i += 256) {
        float4 v = p[i];
        int ei = base_elem + i * 4;
        float sv[4] = {v.x, v.y, v.z, v.w};
        #pragma unroll
        for (int c = 0; c < 4; ++c) {
            float s = sv[c];
            if (s >= SCORE_THR) {
                unsigned fb = __float_as_uint(s);
                if (score_bin(fb) >= bstar) {
                    unsigned pos = atomicAdd(&lcnt, 1u);   // LDS atomic
                    if (pos < CAP) {
                        unsigned idx = (unsigned)(ei + c);
                        lbuf[pos] = ((unsigned long long)fb << 32) | (unsigned)(~idx);
                    }
                }
            }
        }
    }
    __syncthreads();
    unsigned n = lcnt < CAP ? lcnt : CAP;
    if (tid == 0) gbase = atomicAdd(&meta[b].cnt, n);      // one global atomic per block
    __syncthreads();
    unsigned gb = gbase;
    unsigned long long* dst = cand + (size_t)b * CAP;
    for (unsigned i = tid; i < n; i += 256) {
        unsigned o = gb + i;
        if (o < CAP) dst[o] = lbuf[i];
    }
}

__global__ __launch_bounds__(1024) void sort_kernel(const unsigned long long* __restrict__ cand,
                                                    unsigned long long* __restrict__ skey) {
    int b = blockIdx.x;
    __shared__ unsigned long long keys[CAP];   // 32 KB
    for (int i = threadIdx.x; i < CAP; i += 1024)
        keys[i] = cand[(size_t)b * CAP + i];
    __syncthreads();
    // bitonic sort, descending (zeros/padding sink to the end)
    for (int k2 = 2; k2 <= CAP; k2 <<= 1) {
        for (int j = k2 >> 1; j > 0; j >>= 1) {
            for (int idx = threadIdx.x; idx < CAP; idx += 1024) {
                int l = idx ^ j;
                if (l > idx) {
                    unsigned long long a = keys[idx], c = keys[l];
                    bool up = ((idx & k2) == 0);
                    if ((a < c) == up) { keys[idx] = c; keys[l] = a; }
                }
            }
            __syncthreads();
        }
    }
    for (int i = threadIdx.x; i < TOPK; i += 1024)
        skey[(size_t)b * TOPK + i] = keys[i];
}

// Build per-box list of EARLIER adjacent boxes (Chebyshev<=1 on grid cells).
__global__ __launch_bounds__(256) void nbr_kernel(const unsigned long long* __restrict__ skey,
                                                  unsigned long long* __restrict__ nbr2,
                                                  unsigned char* __restrict__ ncnt) {
    int b = blockIdx.y;
    __shared__ unsigned pc[TOPK];
    for (int i = threadIdx.x; i < TOPK; i += 256) {
        unsigned long long key = skey[(size_t)b * TOPK + i];
        unsigned pcv;
        if (key != 0ULL) {
            unsigned idx = ~(unsigned)key;
            pcv = ((idx / W) << 16) | (idx % W);
        } else {
            pcv = 0x40000000u | ((unsigned)i << 2);
        }
        pc[i] = pcv;
    }
    __syncthreads();
    int j = blockIdx.x * 256 + threadIdx.x;  // 0..2047
    unsigned pj = pc[j];
    int yj = (int)(pj >> 16), xj = (int)(pj & 0xFFFFu);
    unsigned long long lp0 = 0, lp1 = 0;
    int cnt = 0;
    for (int i = 0; i < j; ++i) {
        unsigned pi = pc[i];   // broadcast read
        int dy = (int)(pi >> 16) - yj;
        int dx = (int)(pi & 0xFFFFu) - xj;
        if ((unsigned)(dy + 1) <= 2u && (unsigned)(dx + 1) <= 2u) {
            if (cnt < 4)      lp0 |= (unsigned long long)(unsigned)i << (cnt * 16);
            else if (cnt < 8) lp1 |= (unsigned long long)(unsigned)i << ((cnt - 4) * 16);
            cnt++;
        }
    }
    if (cnt > 8) cnt = 8;
    ncnt[(size_t)b * TOPK + j] = (unsigned char)cnt;
    size_t ro = ((size_t)b * TOPK + j) * 2;
    nbr2[ro] = lp0;
    nbr2[ro + 1] = lp1;
}

__global__ __launch_bounds__(256) void nms_out_kernel(const float* __restrict__ dev4,
                                                      const unsigned long long* __restrict__ skey,
                                                      const unsigned long long* __restrict__ nbr2,
                                                      const unsigned char* __restrict__ ncnt,
                                                      float* __restrict__ out) {
    int b = blockIdx.x;
    __shared__ unsigned long long s_nbr[TOPK * 2];  // 32 KB
    __shared__ unsigned char s_cnt[TOPK];
    __shared__ unsigned char s_valid[TOPK];
    __shared__ unsigned char s_kept[TOPK];
    __shared__ unsigned short s_dep[TOPK];
    __shared__ unsigned s_part[256];
    int tid = threadIdx.x;

    for (int i = tid; i < TOPK * 2; i += 256)
        s_nbr[i] = nbr2[(size_t)b * TOPK * 2 + i];

    int nd = 0;
    for (int q = 0; q < 8; ++q) {
        int j = tid * 8 + q;
        unsigned long long key = skey[(size_t)b * TOPK + j];
        unsigned char c = ncnt[(size_t)b * TOPK + j];
        unsigned char v = (key != 0ULL) ? 1 : 0;
        s_cnt[j] = c;
        s_valid[j] = v;
        s_kept[j] = (c == 0) ? v : 0;
        if (c) nd++;
    }
    s_part[tid] = (unsigned)nd;
    __syncthreads();
    for (int off = 1; off < 256; off <<= 1) {
        unsigned v = (tid >= off) ? s_part[tid - off] : 0u;
        __syncthreads();
        s_part[tid] += v;
        __syncthreads();
    }
    int pos = (int)s_part[tid] - nd;
    for (int q = 0; q < 8; ++q) {
        int j = tid * 8 + q;
        if (s_cnt[j]) s_dep[pos++] = (unsigned short)j;
    }
    __syncthreads();

    if (tid == 0) {
        int n = (int)s_part[255];
        for (int e = 0; e < n; ++e) {
            int j = (int)s_dep[e];
            unsigned char k = s_valid[j];
            int c = (int)s_cnt[j];
            for (int l = 0; l < c && k; ++l) {
                unsigned long long w = s_nbr[j * 2 + (l >> 2)];
                unsigned id = (unsigned)((w >> ((l & 3) * 16)) & 0xFFFFu);
                if (s_kept[id]) k = 0;
            }
            s_kept[j] = k;
        }
    }
    __syncthreads();

    for (int j = tid; j < TOPK; j += 256) {
        unsigned long long key = skey[(size_t)b * TOPK + j];
        float o0 = 0.f, o1 = 0.f, o2 = 0.f, o3 = 0.f, o4 = 0.f;
        if (key != 0ULL && s_kept[j]) {
            unsigned idx = ~(unsigned)key;
            float sc = __uint_as_float((unsigned)(key >> 32));
            int y = (int)(idx / W), x = (int)(idx % W);
            const float4 d = ((const float4*)dev4)[(size_t)b * NPROB + idx];
            float b0 = (float)(4 * y + 2);
            float b1 = (float)(4 * x + 2);
            float b2 = (float)(4 * y + 24);
            float b3 = (float)(4 * x + 24);
            float r0 = b0 + d.x * 22.0f;
            float r1 = b1 + d.y * 22.0f;
            float r2 = b2 + d.z * 22.0f;
            float r3 = b3 + d.w * 22.0f;
            float rh = r2 - r0, rw = r3 - r1;
            float len = fmaxf(rh, rw);
            float c0 = r0 + rh * 0.5f, c1v = r1 + rw * 0.5f;
            float u0 = c0 - 0.5f * len, u1 = c1v - 0.5f * len;
            float v0 = u0 + len, v1 = u1 + len;
            o0 = fminf(fmaxf(u0, 1.0f), 3095.0f);
            o1 = fminf(fmaxf(u1, 1.0f), 3095.0f);
            o2 = fminf(fmaxf(v0, 1.0f), 3095.0f);
            o3 = fminf(fmaxf(v1, 1.0f), 3095.0f);
            o4 = sc;
        }
        float* op = out + ((size_t)b * TOPK + j) * 5;
        op[0] = o0; op[1] = o1; op[2] = o2; op[3] = o3; op[4] = o4;
    }
}

extern "C" void kernel_launch(void* const* d_in, const int* in_sizes, int n_in,
                              void* d_out, int out_size, void* d_ws, size_t ws_size,
                              hipStream_t stream) {
    (void)in_sizes; (void)n_in; (void)out_size;
    if (ws_size < (size_t)WS_TOTAL) return;

    const float* probs = (const float*)d_in[0];
    const float* devs  = (const float*)d_in[1];
    float* out = (float*)d_out;
    char* ws = (char*)d_ws;

    unsigned* hist = (unsigned*)(ws + HIST_OFF);
    Meta* meta = (Meta*)(ws + META_OFF);
    unsigned long long* cand = (unsigned long long*)(ws + CAND_OFF);
    unsigned long long* skey = (unsigned long long*)(ws + SKEY_OFF);
    unsigned long long* nbr2 = (unsigned long long*)(ws + NBR_OFF);
    unsigned char* ncnt = (unsigned char*)(ws + NCNT_OFF);

    hipMemsetAsync(d_ws, 0, ZERO_BYTES, stream);

    hist_kernel<<<dim3(NBLK, NB), 256, 0, stream>>>(probs, hist);
    select_kernel<<<NB, 256, 0, stream>>>(hist, meta);
    compact_kernel<<<dim3(NBLK, NB), 256, 0, stream>>>(probs, meta, cand);
    sort_kernel<<<NB, 1024, 0, stream>>>(cand, skey);
    nbr_kernel<<<dim3(TOPK / 256, NB), 256, 0, stream>>>(skey, nbr2, ncnt);
    nms_out_kernel<<<NB, 256, 0, stream>>>(devs, skey, nbr2, ncnt, out);
}

// Round 3
// 91.588 us; speedup vs baseline: 4.7773x; 2.7286x over previous
//
#include <hip/hip_runtime.h>
#include <stdint.h>

#define W 768
#define NPROB (768*768)
#define NB 8
#define NBINS 2048
#define CAP 4096
#define TOPK 2048
#define SCORE_THR 0.6f
#define NBLK 36            // blocks per batch for scan kernels; NPROB = 36*16384
#define HASHN 8192
#define HEMPTY 0xFFFFFFFFu

// ws layout (bytes)
#define HIST_OFF  0
#define HIST_BYTES (NB*NBINS*4)            // 65536
#define META_OFF  (HIST_OFF + HIST_BYTES)
#define CAND_OFF  (META_OFF + 256)
#define CAND_BYTES (NB*CAP*8)              // 262144
#define SKEY_OFF  (CAND_OFF + CAND_BYTES)
#define SKEY_BYTES (NB*TOPK*8)             // 131072
#define ZERO_BYTES (SKEY_OFF + SKEY_BYTES) // zero hist+meta+cand+skey
#define WS_TOTAL  ZERO_BYTES

struct Meta { unsigned bstar; unsigned c1; unsigned cnt; unsigned pad; };

// bin over float bits: valid scores are in [0.6,1.0) -> one binade, bits monotone
__device__ __forceinline__ unsigned score_bin(unsigned fb) {
    return (fb >> 13) & 0x7FFu;
}

__global__ __launch_bounds__(256) void hist_kernel(const float* __restrict__ probs,
                                                   unsigned* __restrict__ hist) {
    __shared__ unsigned lh[NBINS];
    int b = blockIdx.y;
    for (int i = threadIdx.x; i < NBINS; i += 256) lh[i] = 0;
    __syncthreads();
    const int per4 = (NPROB / NBLK) / 4;      // 4096 float4 per block
    const float4* p = (const float4*)(probs + (size_t)b * NPROB) + (size_t)blockIdx.x * per4;
    for (int i = threadIdx.x; i < per4; i += 256) {
        float4 v = p[i];
        if (v.x >= SCORE_THR) atomicAdd(&lh[score_bin(__float_as_uint(v.x))], 1u);
        if (v.y >= SCORE_THR) atomicAdd(&lh[score_bin(__float_as_uint(v.y))], 1u);
        if (v.z >= SCORE_THR) atomicAdd(&lh[score_bin(__float_as_uint(v.z))], 1u);
        if (v.w >= SCORE_THR) atomicAdd(&lh[score_bin(__float_as_uint(v.w))], 1u);
    }
    __syncthreads();
    unsigned* gh = hist + b * NBINS;
    for (int i = threadIdx.x; i < NBINS; i += 256) {
        unsigned v = lh[i];
        if (v) atomicAdd(&gh[i], v);
    }
}

__global__ __launch_bounds__(256) void select_kernel(const unsigned* __restrict__ hist,
                                                     Meta* __restrict__ meta) {
    int b = blockIdx.x;
    const unsigned* h = hist + b * NBINS;
    __shared__ unsigned partial[256];
    int t = threadIdx.x;
    unsigned s = 0;
    for (int i = 0; i < NBINS/256; ++i) s += h[t * (NBINS/256) + i];
    partial[t] = s;
    __syncthreads();
    if (t == 0) {
        const int CH = NBINS / 256;  // 8 bins per chunk
        unsigned cum = 0;
        int chunk = 255;
        for (; chunk >= 0; --chunk) {
            if (cum + partial[chunk] >= TOPK) break;
            cum += partial[chunk];
        }
        unsigned bstar = 0, c1 = cum;
        if (chunk >= 0) {
            int bin = chunk * CH + CH - 1;
            for (; bin >= chunk * CH; --bin) {
                unsigned v = h[bin];
                if (cum + v >= TOPK) break;
                cum += v;
            }
            bstar = (unsigned)bin;
            c1 = cum;
        }
        meta[b].bstar = bstar;
        meta[b].c1 = c1;
    }
}

// Block-local compaction: float4 loads, LDS staging, ONE global atomic per block.
__global__ __launch_bounds__(256) void compact_kernel(const float* __restrict__ probs,
                                                      Meta* __restrict__ meta,
                                                      unsigned long long* __restrict__ cand) {
    __shared__ unsigned long long lbuf[CAP];   // 32 KB
    __shared__ unsigned lcnt;
    __shared__ unsigned gbase;
    int b = blockIdx.y;
    int tid = threadIdx.x;
    if (tid == 0) lcnt = 0;
    __syncthreads();

    unsigned bstar = meta[b].bstar;
    const int per4 = (NPROB / NBLK) / 4;
    int base_elem = blockIdx.x * (NPROB / NBLK);
    const float4* p = (const float4*)(probs + (size_t)b * NPROB) + (size_t)blockIdx.x * per4;
    for (int i = tid; i < per4; i += 256) {
        float4 v = p[i];
        int ei = base_elem + i * 4;
        float sv[4] = {v.x, v.y, v.z, v.w};
        #pragma unroll
        for (int c = 0; c < 4; ++c) {
            float s = sv[c];
            if (s >= SCORE_THR) {
                unsigned fb = __float_as_uint(s);
                if (score_bin(fb) >= bstar) {
                    unsigned pos = atomicAdd(&lcnt, 1u);   // LDS atomic
                    if (pos < CAP) {
                        unsigned idx = (unsigned)(ei + c);
                        lbuf[pos] = ((unsigned long long)fb << 32) | (unsigned)(~idx);
                    }
                }
            }
        }
    }
    __syncthreads();
    unsigned n = lcnt < CAP ? lcnt : CAP;
    if (tid == 0) gbase = atomicAdd(&meta[b].cnt, n);      // one global atomic per block
    __syncthreads();
    unsigned gb = gbase;
    unsigned long long* dst = cand + (size_t)b * CAP;
    for (unsigned i = tid; i < n; i += 256) {
        unsigned o = gb + i;
        if (o < CAP) dst[o] = lbuf[i];
    }
}

// Exact rank by counting: keys are unique (score bits + ~idx), so
// rank = #{y : y > x} reproduces jax top_k order exactly.
__global__ __launch_bounds__(256) void rank_kernel(const unsigned long long* __restrict__ cand,
                                                   const Meta* __restrict__ meta,
                                                   unsigned long long* __restrict__ skey) {
    int b = blockIdx.y;
    __shared__ unsigned long long k[CAP];   // 32 KB
    for (int i = threadIdx.x; i < CAP; i += 256)
        k[i] = cand[(size_t)b * CAP + i];
    __syncthreads();
    unsigned cnt = meta[b].cnt;
    int n = (int)(cnt < CAP ? cnt : CAP);
    int p = blockIdx.x * 256 + threadIdx.x;
    unsigned long long key = k[p];
    if (key != 0ULL) {
        int r = 0;
        int i = 0;
        #pragma unroll 4
        for (; i + 4 <= n; i += 4) {
            r += (k[i]   > key);
            r += (k[i+1] > key);
            r += (k[i+2] > key);
            r += (k[i+3] > key);
        }
        for (; i < n; ++i) r += (k[i] > key);
        if (r < TOPK) skey[(size_t)b * TOPK + r] = key;
    }
}

// Fused: LDS hash (cell->rank) for neighbor discovery (<=8 probes/box),
// monotone fixpoint NMS resolve, refine + write.
__global__ __launch_bounds__(1024) void nms_out_kernel(const float* __restrict__ dev4,
                                                       const unsigned long long* __restrict__ skey,
                                                       float* __restrict__ out) {
    int b = blockIdx.x;
    __shared__ unsigned s_hash[HASHN];       // 32 KB
    __shared__ unsigned char s_state[TOPK];  // 0=undecided 1=kept 2=dead
    __shared__ int s_changed;
    int tid = threadIdx.x;

    for (int i = tid; i < HASHN; i += 1024) s_hash[i] = HEMPTY;
    __syncthreads();

    unsigned long long mykey[2];
    unsigned myidx[2];
    #pragma unroll 2
    for (int q = 0; q < 2; ++q) {
        int j = tid + q * 1024;
        unsigned long long key = skey[(size_t)b * TOPK + j];
        mykey[q] = key;
        if (key != 0ULL) {
            unsigned idx = ~(unsigned)key;
            myidx[q] = idx;
            unsigned val = (idx << 11) | (unsigned)j;   // idx<2^20, j<2^11
            unsigned slot = (idx * 2654435761u >> 19) & (HASHN - 1);
            while (true) {
                unsigned old = atomicCAS(&s_hash[slot], HEMPTY, val);
                if (old == HEMPTY) break;
                slot = (slot + 1) & (HASHN - 1);
            }
        } else {
            myidx[q] = 0;
        }
    }
    __syncthreads();

    // neighbor discovery: 8 surrounding cells, keep earlier ranks (packed 4x16b in 2 u64)
    const int DY[8] = {-1,-1,-1, 0, 0, 1, 1, 1};
    const int DX[8] = {-1, 0, 1,-1, 1,-1, 0, 1};
    unsigned long long np0[2] = {0,0}, np1[2] = {0,0};
    int nc[2] = {0,0};
    #pragma unroll 2
    for (int q = 0; q < 2; ++q) {
        int j = tid + q * 1024;
        if (mykey[q] != 0ULL) {
            int y = (int)(myidx[q] / W), x = (int)(myidx[q] % W);
            int cnt = 0;
            unsigned long long l0 = 0, l1 = 0;
            #pragma unroll
            for (int t = 0; t < 8; ++t) {
                int ny = y + DY[t], nx = x + DX[t];
                if ((unsigned)ny < (unsigned)W && (unsigned)nx < (unsigned)W) {
                    unsigned cell = (unsigned)(ny * W + nx);
                    unsigned slot = (cell * 2654435761u >> 19) & (HASHN - 1);
                    int r = -1;
                    while (true) {
                        unsigned v = s_hash[slot];
                        if (v == HEMPTY) break;
                        if ((v >> 11) == cell) { r = (int)(v & 2047u); break; }
                        slot = (slot + 1) & (HASHN - 1);
                    }
                    if (r >= 0 && r < j) {
                        if (cnt < 4)      l0 |= (unsigned long long)(unsigned)r << (cnt * 16);
                        else              l1 |= (unsigned long long)(unsigned)r << ((cnt - 4) * 16);
                        cnt++;
                    }
                }
            }
            np0[q] = l0; np1[q] = l1; nc[q] = cnt;
        }
        unsigned char st;
        if (mykey[q] == 0ULL) st = 2;
        else st = (nc[q] == 0) ? 1 : 0;
        s_state[j] = st;
    }
    __syncthreads();

    // fixpoint: states move monotonically 0 -> {1,2}; unique fixpoint == greedy NMS
    while (true) {
        __syncthreads();
        if (tid == 0) s_changed = 0;
        __syncthreads();
        bool ch = false;
        #pragma unroll 2
        for (int q = 0; q < 2; ++q) {
            int j = tid + q * 1024;
            if (s_state[j] == 0) {
                bool anyKept = false, anyUnd = false;
                int c = nc[q];
                #pragma unroll
                for (int l = 0; l < 8; ++l) {
                    if (l < c) {
                        unsigned r = (l < 4)
                            ? (unsigned)((np0[q] >> (l * 16)) & 0xFFFFu)
                            : (unsigned)((np1[q] >> ((l - 4) * 16)) & 0xFFFFu);
                        unsigned char st = s_state[r];
                        anyKept |= (st == 1);
                        anyUnd  |= (st == 0);
                    }
                }
                if (anyKept)      { s_state[j] = 2; ch = true; }
                else if (!anyUnd) { s_state[j] = 1; ch = true; }
            }
        }
        if (ch) s_changed = 1;
        __syncthreads();
        if (s_changed == 0) break;
    }

    // refine + write
    #pragma unroll 2
    for (int q = 0; q < 2; ++q) {
        int j = tid + q * 1024;
        float o0 = 0.f, o1 = 0.f, o2 = 0.f, o3 = 0.f, o4 = 0.f;
        if (mykey[q] != 0ULL && s_state[j] == 1) {
            unsigned idx = myidx[q];
            float sc = __uint_as_float((unsigned)(mykey[q] >> 32));
            int y = (int)(idx / W), x = (int)(idx % W);
            const float4 d = ((const float4*)dev4)[(size_t)b * NPROB + idx];
            float b0 = (float)(4 * y + 2);
            float b1 = (float)(4 * x + 2);
            float b2 = (float)(4 * y + 24);
            float b3 = (float)(4 * x + 24);
            float r0 = b0 + d.x * 22.0f;
            float r1 = b1 + d.y * 22.0f;
            float r2 = b2 + d.z * 22.0f;
            float r3 = b3 + d.w * 22.0f;
            float rh = r2 - r0, rw = r3 - r1;
            float len = fmaxf(rh, rw);
            float c0 = r0 + rh * 0.5f, c1v = r1 + rw * 0.5f;
            float u0 = c0 - 0.5f * len, u1 = c1v - 0.5f * len;
            float v0 = u0 + len, v1 = u1 + len;
            o0 = fminf(fmaxf(u0, 1.0f), 3095.0f);
            o1 = fminf(fmaxf(u1, 1.0f), 3095.0f);
            o2 = fminf(fmaxf(v0, 1.0f), 3095.0f);
            o3 = fminf(fmaxf(v1, 1.0f), 3095.0f);
            o4 = sc;
        }
        float* op = out + ((size_t)b * TOPK + j) * 5;
        op[0] = o0; op[1] = o1; op[2] = o2; op[3] = o3; op[4] = o4;
    }
}

extern "C" void kernel_launch(void* const* d_in, const int* in_sizes, int n_in,
                              void* d_out, int out_size, void* d_ws, size_t ws_size,
                              hipStream_t stream) {
    (void)in_sizes; (void)n_in; (void)out_size;
    if (ws_size < (size_t)WS_TOTAL) return;

    const float* probs = (const float*)d_in[0];
    const float* devs  = (const float*)d_in[1];
    float* out = (float*)d_out;
    char* ws = (char*)d_ws;

    unsigned* hist = (unsigned*)(ws + HIST_OFF);
    Meta* meta = (Meta*)(ws + META_OFF);
    unsigned long long* cand = (unsigned long long*)(ws + CAND_OFF);
    unsigned long long* skey = (unsigned long long*)(ws + SKEY_OFF);

    hipMemsetAsync(d_ws, 0, ZERO_BYTES, stream);

    hist_kernel<<<dim3(NBLK, NB), 256, 0, stream>>>(probs, hist);
    select_kernel<<<NB, 256, 0, stream>>>(hist, meta);
    compact_kernel<<<dim3(NBLK, NB), 256, 0, stream>>>(probs, meta, cand);
    rank_kernel<<<dim3(CAP / 256, NB), 256, 0, stream>>>(cand, meta, skey);
    nms_out_kernel<<<NB, 1024, 0, stream>>>(devs, skey, out);
}